// Round 12
// baseline (251.311 us; speedup 1.0000x reference)
//
#include <hip/hip_runtime.h>

// Fused multi-graph GCN inference (N=320k, E=5.12M, features 1->16->16->8->1).
// Layer-1 collapses to a scalar per node; layer-2 uses the relu-threshold bucket
// trick. Edges counting-sorted by dst-range (1024/range), marked-dst edges first.
// R12: k_bucket drops clsL (binary-search class recovery in the coalesced sweep)
// + packed scan -> LDS 59->44 KB, 3 blocks/CU, no tail wave. fillWide folded into
// k_aggS (K>4 branch); wide overlays the partial region (dead after k_s3).

#define MAXB 17
#define RS_BITS 10
#define RS (1 << RS_BITS)
#define SRC_BITS 19
#define SRC_MASK ((1u << SRC_BITS) - 1u)
#define SENT 0xFFFFFFFFu
#define CMAX 160
#define RMAX 320                 // max ranges for new path (N <= 327,680)
#define NPGW_MAX 512             // npg <= 16384
#define HB 512                   // hist blocks
#define BK_BT 512
#define BK_EPT 16
#define BK_TILE (BK_BT * BK_EPT) // 8192
#define PAD4(x) (((x) + 3) & ~3)

__device__ __forceinline__ int div_npg(int d, unsigned long long magic) {
    return (int)(((unsigned long long)(unsigned)d * magic) >> 45);  // exact for d < 2^19
}

__global__ void k_fill_f(float* __restrict__ w, float v, int n) {
    int i = blockIdx.x * blockDim.x + threadIdx.x;
    if (i < n) w[i] = v;
}
__global__ void k_fill_i(int* __restrict__ w, int v, int n) {
    int i = blockIdx.x * blockDim.x + threadIdx.x;
    if (i < n) w[i] = v;
}

// One block: relu-threshold prep + gene table/bitmap + zero hist arrays.
__global__ void k_gprep(const float* __restrict__ W1, const float* __restrict__ b1,
                        const int* __restrict__ gene_idx,
                        float* __restrict__ bnd, int* __restrict__ prepI,
                        int* __restrict__ gmap, unsigned* __restrict__ gbit,
                        int* __restrict__ histT, int* __restrict__ histM,
                        int G, int npg, int npgw, int R) {
    int t = threadIdx.x;
    for (int i = t; i < npg; i += 256) gmap[i] = -1;
    for (int i = t; i < npgw; i += 256) gbit[i] = 0;
    for (int i = t; i < R; i += 256) { histT[i] = 0; histM[i] = 0; }
    __syncthreads();
    for (int g = t; g < G; g += 256) {
        int gi = gene_idx[g];
        if ((unsigned)gi < (unsigned)npg) {
            gmap[gi] = g;
            atomicOr(&gbit[gi >> 5], 1u << (gi & 31));
        }
    }
    if (t != 0) return;
    float tt[16]; int type[16]; int pos[16];
    float thr[16]; int nt = 0;
    for (int j = 0; j < 16; j++) {
        float W = W1[j], B = b1[j];
        if (W > 0.f)      { type[j] = 0; tt[j] = -B / W; }
        else if (W < 0.f) { type[j] = 1; tt[j] = -B / W; }
        else              { type[j] = (B > 0.f) ? 2 : 3; tt[j] = 0.f; }
    }
    for (int j = 0; j < 16; j++) {
        if (type[j] > 1) continue;
        float v = tt[j];
        int k = 0; while (k < nt && thr[k] < v) k++;
        if (!(k < nt && thr[k] == v)) {
            for (int m = nt; m > k; m--) thr[m] = thr[m - 1];
            thr[k] = v; nt++;
        }
    }
    int K = nt + 1;
    for (int j = 0; j < 16; j++) {
        if (type[j] <= 1) { int k = 0; while (thr[k] != tt[j]) k++; pos[j] = k; }
        else pos[j] = 0;
    }
    for (int k = 0; k < 16; k++) bnd[k] = (k < nt) ? thr[k] : 3.4e38f;
    prepI[0] = K;
    for (int k = 0; k < K; k++) {
        unsigned m = 0;
        for (int j = 0; j < 16; j++) {
            bool act;
            if (type[j] == 0)      act = (k >= pos[j] + 1);
            else if (type[j] == 1) act = (k <= pos[j]);
            else                   act = (type[j] == 2);
            if (act) m |= (1u << j);
        }
        prepI[1 + k] = (int)m;
    }
}

// Fused: blocks [0,R) build cmap/cslot/mc; blocks [R,R+HB) histogram dst ranges.
__global__ void k_cmap_hist(const int* __restrict__ gmap, const unsigned* __restrict__ gbit,
                            const int* __restrict__ dst,
                            int* __restrict__ cm, int* __restrict__ cslot, int* __restrict__ mc,
                            int* __restrict__ histT, int* __restrict__ histM,
                            int N, int R, int npg, int reps, int G, int E, int npgw,
                            unsigned long long magic) {
    __shared__ unsigned bitL[NPGW_MAX];
    for (int i = threadIdx.x; i < npgw; i += 256) bitL[i] = gbit[i];
    if (blockIdx.x < (unsigned)R) {
        __shared__ int cnt;
        if (threadIdx.x == 0) cnt = 0;
        __syncthreads();
        int r = blockIdx.x;
        int b0 = r << RS_BITS;
        for (int i = threadIdx.x; i < RS; i += 256) {
            int v = b0 + i;
            if (v >= N) continue;
            int rep = div_npg(v, magic);
            int gi = v - rep * npg;
            int out = -1;
            if (rep < reps && ((bitL[gi >> 5] >> (gi & 31)) & 1u)) {
                int g = gmap[gi];
                if (g >= 0) {
                    int sl = rep * G + g;
                    int c = atomicAdd(&cnt, 1);
                    if (c < CMAX) { cslot[r * CMAX + c] = sl; out = c; }
                    else out = -(sl + 2);
                }
            }
            cm[v] = out;
        }
        __syncthreads();
        if (threadIdx.x == 0) mc[r] = min(cnt, CMAX);
    } else {
        __shared__ int hT[RMAX], hM[RMAX];
        for (int i = threadIdx.x; i < R; i += 256) { hT[i] = 0; hM[i] = 0; }
        __syncthreads();
        int hb = blockIdx.x - R;
        int stride = HB * 256;
        int E4 = E >> 2;
        const int4* d4p = (const int4*)dst;
        for (int e = hb * 256 + threadIdx.x; e < E4; e += stride) {
            int4 d4 = d4p[e];
            int dd[4] = {d4.x, d4.y, d4.z, d4.w};
#pragma unroll
            for (int k = 0; k < 4; k++) {
                int d = dd[k];
                if ((unsigned)d >= (unsigned)N) continue;
                atomicAdd(&hT[d >> RS_BITS], 1);
                int rep = div_npg(d, magic);
                int gi = d - rep * npg;
                if (rep < reps && ((bitL[gi >> 5] >> (gi & 31)) & 1u))
                    atomicAdd(&hM[d >> RS_BITS], 1);
            }
        }
        for (int e = (E4 << 2) + hb * 256 + threadIdx.x; e < E; e += stride) {
            int d = dst[e];
            if ((unsigned)d >= (unsigned)N) continue;
            atomicAdd(&hT[d >> RS_BITS], 1);
            int rep = div_npg(d, magic);
            int gi = d - rep * npg;
            if (rep < reps && ((bitL[gi >> 5] >> (gi & 31)) & 1u))
                atomicAdd(&hM[d >> RS_BITS], 1);
        }
        __syncthreads();
        for (int i = threadIdx.x; i < R; i += 256) {
            if (hT[i]) atomicAdd(&histT[i], hT[i]);
            if (hM[i]) atomicAdd(&histM[i], hM[i]);
        }
    }
}

// Scan padded segment sizes; init packed cursors; write pad-gap sentinels (<=6/range).
__global__ void k_scan(const int* __restrict__ histT, const int* __restrict__ histM,
                       int* __restrict__ baseA, unsigned long long* __restrict__ cur64,
                       unsigned* __restrict__ bucket, int R, int cap) {
    __shared__ int a[512];
    int t = threadIdx.x;
    int m = (t < R) ? histM[t] : 0;
    int tot = (t < R) ? histT[t] : 0;
    int u = tot - m; if (u < 0) u = 0;
    int seg = PAD4(m) + PAD4(u);
    a[t] = seg;
    __syncthreads();
    for (int off = 1; off < 512; off <<= 1) {
        int add = (t >= off) ? a[t - off] : 0;
        __syncthreads();
        a[t] += add;
        __syncthreads();
    }
    if (t < R) {
        int base = a[t] - seg;
        baseA[t] = base;
        int mstart = base, ustart = base + PAD4(m);
        cur64[t] = (unsigned long long)(unsigned)mstart |
                   ((unsigned long long)(unsigned)ustart << 32);
        for (int i = m; i < PAD4(m); i++) { int ix = mstart + i; if (ix < cap) bucket[ix] = SENT; }
        for (int i = u; i < PAD4(u); i++) { int ix = ustart + i; if (ix < cap) bucket[ix] = SENT; }
    }
}

// Dual-class bucket scatter: per-tile LDS counting sort + coalesced sweep.
// Class of each swept element recovered by binary search in eb[] (no clsL array).
__global__ void __launch_bounds__(BK_BT)
k_bucket(const int* __restrict__ src, const int* __restrict__ dst,
         const unsigned* __restrict__ gbit, unsigned long long* __restrict__ cur64,
         unsigned* __restrict__ bucket, int E, int N, int R, int cap,
         int npg, int reps, int npgw, unsigned long long magic) {
    __shared__ unsigned bitL[NPGW_MAX];          // 2 KB
    __shared__ int cntA[RMAX];                   // packed m|u<<16 counts
    __shared__ int cnt2[RMAX];                   // packed placement counters
    __shared__ int sc[RMAX];                     // packed inclusive scan
    __shared__ int eb[2 * RMAX + 1];             // class exclusive bases (sorted)
    __shared__ int dl[2 * RMAX];                 // global - local delta per class
    __shared__ unsigned sortL[BK_TILE];          // 32 KB
    __shared__ int totalS;

    for (int i = threadIdx.x; i < npgw; i += BK_BT) bitL[i] = gbit[i];
    for (int i = threadIdx.x; i < R; i += BK_BT) { cntA[i] = 0; cnt2[i] = 0; }
    __syncthreads();

    int tile0 = blockIdx.x * BK_TILE;
    int rr[BK_EPT]; unsigned val[BK_EPT]; unsigned mbits = 0;
    // phase 1: read + classify + per-range packed count
#pragma unroll
    for (int c = 0; c < 4; c++) {
        int e0 = tile0 + c * (BK_BT * 4) + threadIdx.x * 4;
        int dd[4], ss[4];
        if (e0 + 3 < E) {
            int4 d4 = *(const int4*)(dst + e0);
            int4 s4 = *(const int4*)(src + e0);
            dd[0] = d4.x; dd[1] = d4.y; dd[2] = d4.z; dd[3] = d4.w;
            ss[0] = s4.x; ss[1] = s4.y; ss[2] = s4.z; ss[3] = s4.w;
        } else {
#pragma unroll
            for (int k = 0; k < 4; k++) {
                int e = e0 + k;
                dd[k] = (e < E) ? dst[e] : -1;
                ss[k] = (e < E) ? src[e] : -1;
            }
        }
#pragma unroll
        for (int k = 0; k < 4; k++) {
            int idx = c * 4 + k;
            int d = dd[k];
            rr[idx] = -1;
            if ((unsigned)d < (unsigned)N) {
                int rep = div_npg(d, magic);
                int gi = d - rep * npg;
                unsigned m = (rep < reps && ((bitL[gi >> 5] >> (gi & 31)) & 1u)) ? 1u : 0u;
                int s = ss[k];
                rr[idx] = d >> RS_BITS;
                val[idx] = ((unsigned)s < (unsigned)N)
                               ? (((unsigned)(d & (RS - 1)) << SRC_BITS) | (unsigned)s)
                               : SENT;
                mbits |= m << idx;
                atomicAdd(&cntA[d >> RS_BITS], m ? 1 : (1 << 16));
            }
        }
    }
    __syncthreads();
    // phase 2: packed inclusive scan over R entries; derive class exclusive bases
    int t = threadIdx.x;
    for (int i = t; i < R; i += BK_BT) sc[i] = cntA[i];
    __syncthreads();
    for (int off = 1; off < R; off <<= 1) {
        int v = 0;
        if (t < R && t >= off) v = sc[t - off];
        __syncthreads();
        if (t < R && t >= off) sc[t] += v;
        __syncthreads();
    }
    if (t == 0) {
        int tp = sc[R - 1];
        totalS = (tp & 0xFFFF) + (tp >> 16);
        eb[2 * R] = totalS;
    }
    __syncthreads();
    {
        int total_m = sc[R - 1] & 0xFFFF;
        if (t < R) {
            int inc = sc[t], c = cntA[t];
            eb[t]     = (inc & 0xFFFF) - (c & 0xFFFF);
            eb[R + t] = total_m + (inc >> 16) - (c >> 16);
        }
    }
    __syncthreads();
    // phase 3: one packed 64-bit global reservation per range; deltas per class
    for (int r = t; r < R; r += BK_BT) {
        int c = cntA[r];
        if (c) {
            unsigned long long add = (unsigned long long)(c & 0xFFFF) |
                                     ((unsigned long long)(unsigned)(c >> 16) << 32);
            unsigned long long old = atomicAdd(&cur64[r], add);
            dl[r]     = (int)(old & 0xFFFFFFFFull) - eb[r];
            dl[R + r] = (int)(old >> 32)           - eb[R + r];
        }
    }
    __syncthreads();
    // phase 4: place into LDS in class-major sorted order
#pragma unroll
    for (int i = 0; i < BK_EPT; i++) {
        int r = rr[i];
        if (r < 0) continue;
        unsigned m = (mbits >> i) & 1u;
        int o = atomicAdd(&cnt2[r], m ? 1 : (1 << 16));
        int cidx = m ? r : (R + r);
        int loc = m ? (o & 0xFFFF) : (o >> 16);
        sortL[eb[cidx] + loc] = val[i];
    }
    __syncthreads();
    // phase 5: coalesced sweep; class via binary search in eb (wave-uniform path)
    int total = totalS;
    int n2 = 2 * R;
    for (int i = t; i < total; i += BK_BT) {
        int lo = 0, hi = n2;
        while (hi - lo > 1) {
            int mid = (lo + hi) >> 1;
            if (eb[mid] <= i) lo = mid; else hi = mid;
        }
        int addr = dl[lo] + i;
        if ((unsigned)addr < (unsigned)cap) bucket[addr] = sortL[i];
    }
}

// ---------- sub-blocked per-range passes ----------

__global__ void __launch_bounds__(1024)
k_degR2(const unsigned* __restrict__ bucket, const int* __restrict__ baseA,
        const int* __restrict__ histT, const int* __restrict__ histM,
        int* __restrict__ pDeg, int cap, int S) {
    __shared__ int degL[RS];
    int r = blockIdx.x / S, q = blockIdx.x % S;
    int m = histM[r];
    int u = histT[r] - m; if (u < 0) u = 0;
    int nb = baseA[r];
    int len = min(PAD4(m) + PAD4(u), cap - nb);
    if (len < 0) len = 0;
    int lo = (int)(((long long)len * q / S) & ~3LL);
    int hi = (q == S - 1) ? len : (int)(((long long)len * (q + 1) / S) & ~3LL);
    for (int i = threadIdx.x; i < RS; i += blockDim.x) degL[i] = 0;
    __syncthreads();
    for (int i = lo + threadIdx.x * 4; i < hi; i += blockDim.x * 4) {
        uint4 e4 = *(const uint4*)(bucket + nb + i);
        if (i + 0 < hi && e4.x != SENT) atomicAdd(&degL[e4.x >> SRC_BITS], 1);
        if (i + 1 < hi && e4.y != SENT) atomicAdd(&degL[e4.y >> SRC_BITS], 1);
        if (i + 2 < hi && e4.z != SENT) atomicAdd(&degL[e4.z >> SRC_BITS], 1);
        if (i + 3 < hi && e4.w != SENT) atomicAdd(&degL[e4.w >> SRC_BITS], 1);
    }
    __syncthreads();
    int* out = pDeg + (size_t)(r * S + q) * RS;
    for (int i = threadIdx.x; i < RS; i += blockDim.x) out[i] = degL[i];
}

__global__ void k_dinvp2(const int* __restrict__ pDeg, const float* __restrict__ x,
                         float* __restrict__ sd, float* __restrict__ p, int N, int S) {
    int v = blockIdx.x * blockDim.x + threadIdx.x;
    if (v >= N) return;
    int r = v >> RS_BITS, l = v & (RS - 1);
    int deg = 0;
    for (int q = 0; q < S; q++) deg += pDeg[(size_t)(r * S + q) * RS + l];
    float di = rsqrtf((float)deg + 1.0f);
    sd[2 * v + 1] = di;
    p[v] = x[v] * di;
}

__global__ void __launch_bounds__(1024)
k_t1R2(const unsigned* __restrict__ bucket, const int* __restrict__ baseA,
       const int* __restrict__ histT, const int* __restrict__ histM,
       const float* __restrict__ p, float* __restrict__ pT1, int cap, int S) {
    __shared__ float accL[RS];
    int r = blockIdx.x / S, q = blockIdx.x % S;
    int m = histM[r];
    int u = histT[r] - m; if (u < 0) u = 0;
    int nb = baseA[r];
    int len = min(PAD4(m) + PAD4(u), cap - nb);
    if (len < 0) len = 0;
    int lo = (int)(((long long)len * q / S) & ~3LL);
    int hi = (q == S - 1) ? len : (int)(((long long)len * (q + 1) / S) & ~3LL);
    for (int i = threadIdx.x; i < RS; i += blockDim.x) accL[i] = 0.f;
    __syncthreads();
    for (int i = lo + threadIdx.x * 4; i < hi; i += blockDim.x * 4) {
        uint4 e4 = *(const uint4*)(bucket + nb + i);
        if (i + 0 < hi && e4.x != SENT) atomicAdd(&accL[e4.x >> SRC_BITS], p[e4.x & SRC_MASK]);
        if (i + 1 < hi && e4.y != SENT) atomicAdd(&accL[e4.y >> SRC_BITS], p[e4.y & SRC_MASK]);
        if (i + 2 < hi && e4.z != SENT) atomicAdd(&accL[e4.z >> SRC_BITS], p[e4.z & SRC_MASK]);
        if (i + 3 < hi && e4.w != SENT) atomicAdd(&accL[e4.w >> SRC_BITS], p[e4.w & SRC_MASK]);
    }
    __syncthreads();
    float* out = pT1 + (size_t)(r * S + q) * RS;
    for (int i = threadIdx.x; i < RS; i += blockDim.x) out[i] = accL[i];
}

// s[v] = dinv*(t1+p) -> sd[2v]; also zero-fills aggb8.
__global__ void k_s3(const float* __restrict__ pT1, const float* __restrict__ p,
                     float* __restrict__ sd, float* __restrict__ aggb8, int n8,
                     int N, int S) {
    int v = blockIdx.x * blockDim.x + threadIdx.x;
    if (v < n8) aggb8[v] = 0.f;
    if (v >= N) return;
    int r = v >> RS_BITS, l = v & (RS - 1);
    float t1 = 0.f;
    for (int q = 0; q < S; q++) t1 += pT1[(size_t)(r * S + q) * RS + l];
    sd[2 * v] = sd[2 * v + 1] * (t1 + p[v]);
}

// Layer-2 bucket sums over marked prefix (K<=4; compact rows -> plain stores).
// K>4: grid-stride zero of wide (which overlays the now-dead partial region);
// the subsequent k_agg_atomic dispatch then accumulates into it.
__global__ void k_aggS(const unsigned* __restrict__ bucket, const int* __restrict__ baseA,
                       const int* __restrict__ histM,
                       const float* __restrict__ sd, const int* __restrict__ cm,
                       const int* __restrict__ cslot, const int* __restrict__ mc,
                       const float* __restrict__ bnd, const int* __restrict__ prepI,
                       float* __restrict__ aggb8, float* __restrict__ wide, int wn,
                       int N, int cap) {
    __shared__ float acc[CMAX * 8];
    __shared__ int cmapL[RS];
    __shared__ float sB[3];
    __shared__ int sK;
    if (threadIdx.x == 0) sK = prepI[0];
    if (threadIdx.x < 3) sB[threadIdx.x] = bnd[threadIdx.x];
    __syncthreads();
    int K = sK;
    if (K > 4) {
        for (int i = blockIdx.x * blockDim.x + threadIdx.x; i < wn;
             i += gridDim.x * blockDim.x)
            wide[i] = 0.f;
        return;
    }
    int r = blockIdx.x;
    int b0 = r << RS_BITS;
    for (int i = threadIdx.x; i < RS; i += 256) {
        int v = b0 + i;
        cmapL[i] = (v < N) ? cm[v] : -1;
    }
    for (int i = threadIdx.x; i < CMAX * 8; i += 256) acc[i] = 0.f;
    __syncthreads();
    int nb = baseA[r];
    int mlen = min(histM[r], cap - nb);
    if (mlen < 0) mlen = 0;
    const float2* sd2 = (const float2*)sd;
    for (int i = threadIdx.x * 4; i < mlen; i += 256 * 4) {
        uint4 e4 = *(const uint4*)(bucket + nb + i);
        unsigned ee[4] = {e4.x, e4.y, e4.z, e4.w};
#pragma unroll
        for (int k4 = 0; k4 < 4; k4++) {
            if (i + k4 >= mlen) break;
            unsigned e = ee[k4];
            if (e == SENT) continue;
            int c = cmapL[e >> SRC_BITS];
            if (c == -1) continue;
            float2 v = sd2[e & SRC_MASK];
            int b = 0;
            for (int k = 0; k < K - 1; k++) b += (v.x > sB[k]) ? 1 : 0;
            if (c >= 0) {
                atomicAdd(&acc[c * 8 + 2 * b], v.x * v.y);
                atomicAdd(&acc[c * 8 + 2 * b + 1], v.y);
            } else {
                int sl = -(c + 2);
                atomicAdd(&aggb8[(size_t)sl * 8 + 2 * b], v.x * v.y);
                atomicAdd(&aggb8[(size_t)sl * 8 + 2 * b + 1], v.y);
            }
        }
    }
    __syncthreads();
    int mcR = mc[r];
    for (int idx = threadIdx.x; idx < mcR * 8; idx += 256) {
        int c = idx >> 3, j = idx & 7;
        int sl = cslot[r * CMAX + c];
        if (sl >= 0) aggb8[(size_t)sl * 8 + j] = acc[idx];
    }
}

// ---------- generic / fallback kernels ----------

__global__ void k_mark(const int* __restrict__ gene_idx, int* __restrict__ slot,
                       int G, int M, int npg, int N) {
    int i = blockIdx.x * blockDim.x + threadIdx.x;
    if (i >= M) return;
    int node = gene_idx[i % G] + (i / G) * npg;
    if ((unsigned)node < (unsigned)N) slot[node] = i;
}

__global__ void k_deg(const int* __restrict__ dst, float* __restrict__ deg, int E, int N) {
    int e = blockIdx.x * blockDim.x + threadIdx.x;
    if (e >= E) return;
    int d = dst[e];
    if ((unsigned)d < (unsigned)N) atomicAdd(&deg[d], 1.0f);
}

__global__ void k_dinv_p(const float* __restrict__ x, float* __restrict__ degv,
                         float* __restrict__ p, int N) {
    int v = blockIdx.x * blockDim.x + threadIdx.x;
    if (v < N) {
        float di = rsqrtf(degv[v] + 1.0f);
        degv[v] = di;
        p[v] = x[v] * di;
    }
}

__global__ void k_scatter1(const int* __restrict__ src, const int* __restrict__ dst,
                           const float* __restrict__ p, float* __restrict__ t1, int E, int N) {
    int e = blockIdx.x * blockDim.x + threadIdx.x;
    if (e >= E) return;
    int s = src[e];
    int d = dst[e];
    if ((unsigned)s < (unsigned)N && (unsigned)d < (unsigned)N)
        atomicAdd(&t1[d], p[s]);
}

__global__ void k_s(const float* __restrict__ p, const float* __restrict__ dinv,
                    float* __restrict__ t1, int N) {
    int v = blockIdx.x * blockDim.x + threadIdx.x;
    if (v < N) t1[v] = dinv[v] * (t1[v] + p[v]);
}

__global__ void k_agg_atomic(const int* __restrict__ src, const int* __restrict__ dst,
                             const float* __restrict__ sA, const float* __restrict__ dA,
                             int str, const int* __restrict__ cm, const int* __restrict__ cslot,
                             const float* __restrict__ bnd, const int* __restrict__ prepI,
                             float* __restrict__ wide, int E, int N, int force, int mode) {
    __shared__ float sB[16];
    __shared__ int sK;
    if (threadIdx.x == 0) sK = prepI[0];
    if (threadIdx.x < 16) sB[threadIdx.x] = bnd[threadIdx.x];
    __syncthreads();
    int K = sK;
    if (!force && K <= 4) return;
    int T = K - 1;
    for (int e = blockIdx.x * blockDim.x + threadIdx.x; e < E; e += gridDim.x * blockDim.x) {
        int d = dst[e];
        if ((unsigned)d >= (unsigned)N) continue;
        int c = cm[d];
        int sl;
        if (mode == 0) sl = c;
        else sl = (c >= 0) ? cslot[(d >> RS_BITS) * CMAX + c] : (c <= -2 ? -(c + 2) : -1);
        if (sl < 0) continue;
        int sv = src[e];
        if ((unsigned)sv >= (unsigned)N) continue;
        float sval = sA[(size_t)sv * str];
        float di = dA[(size_t)sv * str];
        int b = 0;
        for (int i = 0; i < T; i++) b += (sval > sB[i]) ? 1 : 0;
        float* row = wide + (size_t)sl * (2 * MAXB) + 2 * b;
        atomicAdd(row, sval * di);
        atomicAdd(row + 1, di);
    }
}

__global__ void k_final(const float* __restrict__ aggb8, const float* __restrict__ wide,
                        const float* __restrict__ sA, const float* __restrict__ dA, int str,
                        const int* __restrict__ gene_idx, const int* __restrict__ cm,
                        const int* __restrict__ cslot, const int* __restrict__ prepI,
                        const float* __restrict__ W1, const float* __restrict__ b1,
                        const float* __restrict__ W2, const float* __restrict__ b2,
                        const float* __restrict__ f1W, const float* __restrict__ f1b,
                        const float* __restrict__ f2W, const float* __restrict__ f2b,
                        float* __restrict__ out, int G, int M, int npg, int N, int mode) {
    __shared__ float sW1[16], sb1[16], sW2[256], sb2[16], sf1[128], sf1b[8], sf2[8], sf2b[1];
    __shared__ int sMask[MAXB], sK;
    for (int i = threadIdx.x; i < 256; i += blockDim.x) sW2[i] = W2[i];
    for (int i = threadIdx.x; i < 128; i += blockDim.x) sf1[i] = f1W[i];
    if (threadIdx.x < 16) { sW1[threadIdx.x] = W1[threadIdx.x]; sb1[threadIdx.x] = b1[threadIdx.x]; sb2[threadIdx.x] = b2[threadIdx.x]; }
    if (threadIdx.x < 8)  { sf1b[threadIdx.x] = f1b[threadIdx.x]; sf2[threadIdx.x] = f2W[threadIdx.x]; }
    if (threadIdx.x == 0) { sf2b[0] = f2b[0]; sK = prepI[0]; }
    if (threadIdx.x < MAXB) sMask[threadIdx.x] = prepI[1 + threadIdx.x];
    __syncthreads();

    int i = blockIdx.x * blockDim.x + threadIdx.x;
    if (i >= M) return;
    int node = gene_idx[i % G] + (i / G) * npg;
    if ((unsigned)node >= (unsigned)N) { out[i] = 0.0f; return; }
    int K = sK;
    int c = cm[node];
    int sl;
    if (mode == 0) sl = c;
    else sl = (c >= 0) ? cslot[(node >> RS_BITS) * CMAX + c] : (c <= -2 ? -(c + 2) : -1);

    float di = dA[(size_t)node * str];
    float sval = sA[(size_t)node * str];

    float bu[MAXB], bw[MAXB];
    if (sl >= 0) {
        const float* row = (mode == 1 && K <= 4) ? (aggb8 + (size_t)sl * 8)
                                                 : (wide + (size_t)sl * (2 * MAXB));
        for (int k = 0; k < K; k++) { bu[k] = row[2 * k]; bw[k] = row[2 * k + 1]; }
    } else {
        for (int k = 0; k < K; k++) { bu[k] = 0.f; bw[k] = 0.f; }
    }

    float a[16];
#pragma unroll
    for (int j = 0; j < 16; j++) {
        float Su = 0.f, Sw = 0.f;
        for (int k = 0; k < K; k++) {
            if ((sMask[k] >> j) & 1) { Su += bu[k]; Sw += bw[k]; }
        }
        float aggj = sW1[j] * Su + sb1[j] * Sw;
        float qself = fmaxf(fmaf(sW1[j], sval, sb1[j]), 0.0f) * di;
        a[j] = di * (aggj + qself);
    }
    float h2[16];
#pragma unroll
    for (int j = 0; j < 16; j++) {
        float acc = sb2[j];
#pragma unroll
        for (int k = 0; k < 16; k++) acc = fmaf(a[k], sW2[k * 16 + j], acc);
        h2[j] = fmaxf(acc, 0.0f);
    }
    float f1[8];
#pragma unroll
    for (int j = 0; j < 8; j++) {
        float acc = sf1b[j];
#pragma unroll
        for (int k = 0; k < 16; k++) acc = fmaf(h2[k], sf1[k * 8 + j], acc);
        f1[j] = fmaxf(acc, 0.0f);
    }
    float o = sf2b[0];
#pragma unroll
    for (int k = 0; k < 8; k++) o = fmaf(f1[k], sf2[k], o);
    out[i] = o;
}

extern "C" void kernel_launch(void* const* d_in, const int* in_sizes, int n_in,
                              void* d_out, int out_size, void* d_ws, size_t ws_size,
                              hipStream_t stream) {
    const float* x        = (const float*)d_in[0];
    const int*   ei       = (const int*)d_in[1];
    const int*   gene_idx = (const int*)d_in[3];
    const float* W1  = (const float*)d_in[5];
    const float* b1  = (const float*)d_in[6];
    const float* W2  = (const float*)d_in[7];
    const float* b2  = (const float*)d_in[8];
    const float* f1W = (const float*)d_in[9];
    const float* f1b = (const float*)d_in[10];
    const float* f2W = (const float*)d_in[11];
    const float* f2b = (const float*)d_in[12];
    float* out = (float*)d_out;

    int N = in_sizes[0];       // 320000
    int E = in_sizes[1] / 2;   // 5120000
    int M = in_sizes[2];       // 32000
    int G = in_sizes[3];       // 1000
    int npg = (int)(((long long)N * (long long)G) / (long long)M);
    int reps = (G > 0) ? M / G : 0;
    int npgw = (npg + 31) / 32;
    unsigned long long magic = (npg >= 1) ? (((1ULL << 45) + npg - 1) / (unsigned)npg) : 1;

    const int* src = ei;
    const int* dst = ei + E;

    int R = (N + RS - 1) >> RS_BITS;
    int cap = E + 8 * R + 8;
    const int tb = 256;
    int wn = 2 * MAXB * M;

    float* ws = (float*)d_ws;
    size_t off = 0;
    float*    sd     = ws + off;              off += (size_t)2 * N;
    int*      cm     = (int*)(ws + off);      off += (size_t)N;
    float*    p      = ws + off;              off += (size_t)N;
    float*    aggb8  = ws + off;              off += (size_t)8 * M;
    unsigned* bucket = (unsigned*)(ws + off); off += (size_t)cap;
    int*      gmap   = (int*)(ws + off);      off += (size_t)npg;
    unsigned* gbit   = (unsigned*)(ws + off); off += (size_t)npgw;
    int*      cslot  = (int*)(ws + off);      off += (size_t)R * CMAX;
    int*      mc     = (int*)(ws + off);      off += (size_t)R;
    int*      histT  = (int*)(ws + off);      off += (size_t)R;
    int*      histM  = (int*)(ws + off);      off += (size_t)R;
    int*      baseA  = (int*)(ws + off);      off += (size_t)R;
    off = (off + 1) & ~(size_t)1;             // 8B align
    unsigned long long* cur64 = (unsigned long long*)(ws + off); off += (size_t)2 * R;
    float*    bnd    = ws + off;              off += 16;
    int*      prepI  = (int*)(ws + off);      off += 20;
    size_t base_need = off;

    int S = 4;
    while (S > 1 && (base_need + (size_t)R * S * RS) * 4 > ws_size) S >>= 1;
    float* partial = ws + base_need;
    int*   partialI = (int*)partial;
    float* wide = partial;                    // overlays partial (dead after k_s3)
    size_t need = (base_need + (size_t)R * S * RS) * 4;

    bool use_new = (need <= ws_size) && (N < (1 << SRC_BITS)) && (R <= RMAX) &&
                   (npg >= 1) && (npg <= NPGW_MAX * 32) && (reps >= 1) &&
                   ((size_t)R * S * RS >= (size_t)wn);

    if (use_new) {
        int BTr = (S == 1) ? 1024 : 256;
        k_gprep<<<1, 256, 0, stream>>>(W1, b1, gene_idx, bnd, prepI, gmap, gbit,
                                       histT, histM, G, npg, npgw, R);
        k_cmap_hist<<<R + HB, 256, 0, stream>>>(gmap, gbit, dst, cm, cslot, mc,
                                                histT, histM, N, R, npg, reps, G, E,
                                                npgw, magic);
        k_scan<<<1, 512, 0, stream>>>(histT, histM, baseA, cur64, bucket, R, cap);
        int ntiles = (E + BK_TILE - 1) / BK_TILE;
        k_bucket<<<ntiles, BK_BT, 0, stream>>>(src, dst, gbit, cur64, bucket,
                                               E, N, R, cap, npg, reps, npgw, magic);
        k_degR2<<<R * S, BTr, 0, stream>>>(bucket, baseA, histT, histM, partialI, cap, S);
        k_dinvp2<<<(N + tb - 1) / tb, tb, 0, stream>>>(partialI, x, sd, p, N, S);
        k_t1R2<<<R * S, BTr, 0, stream>>>(bucket, baseA, histT, histM, p, partial, cap, S);
        int n8 = 8 * M;
        int s3grid = ((N > n8 ? N : n8) + tb - 1) / tb;
        k_s3<<<s3grid, tb, 0, stream>>>(partial, p, sd, aggb8, n8, N, S);
        k_aggS<<<R, tb, 0, stream>>>(bucket, baseA, histM, sd, cm, cslot, mc,
                                     bnd, prepI, aggb8, wide, wn, N, cap);
        k_agg_atomic<<<512, tb, 0, stream>>>(src, dst, sd, sd + 1, 2, cm, cslot, bnd,
                                             prepI, wide, E, N, /*force=*/0, /*mode=*/1);
        k_final<<<(M + tb - 1) / tb, tb, 0, stream>>>(aggb8, wide, sd, sd + 1, 2, gene_idx,
                                                      cm, cslot, prepI, W1, b1, W2, b2,
                                                      f1W, f1b, f2W, f2b, out, G, M, npg, N,
                                                      /*mode=*/1);
    } else {
        // Fallback: global-atomic path, wide layout.
        float* deg   = ws;
        float* t1o   = ws + (size_t)N;
        float* pO    = ws + 2 * (size_t)N;
        int*   slotO = (int*)(ws + 3 * (size_t)N);
        float* wideO = ws + 4 * (size_t)N;
        float* bndO  = wideO + (size_t)wn;
        int*   prepO = (int*)(bndO + 16);
        int*   scr   = prepO + 20;

        k_fill_f<<<(2 * N + tb - 1) / tb, tb, 0, stream>>>(deg, 0.0f, 2 * N);
        k_fill_i<<<(N + tb - 1) / tb, tb, 0, stream>>>(slotO, -1, N);
        k_fill_f<<<(wn + tb - 1) / tb, tb, 0, stream>>>(wideO, 0.0f, wn);
        k_gprep<<<1, 256, 0, stream>>>(W1, b1, gene_idx, bndO, prepO,
                                       scr, (unsigned*)(scr + 1), scr + 2, scr + 3,
                                       0, 1, 1, 0);
        k_mark<<<(M + tb - 1) / tb, tb, 0, stream>>>(gene_idx, slotO, G, M, npg, N);
        k_deg<<<(E + tb - 1) / tb, tb, 0, stream>>>(dst, deg, E, N);
        k_dinv_p<<<(N + tb - 1) / tb, tb, 0, stream>>>(x, deg, pO, N);
        k_scatter1<<<(E + tb - 1) / tb, tb, 0, stream>>>(src, dst, pO, t1o, E, N);
        k_s<<<(N + tb - 1) / tb, tb, 0, stream>>>(pO, deg, t1o, N);
        k_agg_atomic<<<2048, tb, 0, stream>>>(src, dst, t1o, deg, 1, slotO, (int*)0, bndO,
                                              prepO, wideO, E, N, /*force=*/1, /*mode=*/0);
        k_final<<<(M + tb - 1) / tb, tb, 0, stream>>>((float*)0, wideO, t1o, deg, 1, gene_idx,
                                                      slotO, (int*)0, prepO, W1, b1, W2, b2,
                                                      f1W, f1b, f2W, f2b, out, G, M, npg, N,
                                                      /*mode=*/0);
    }
}

// Round 13
// 246.408 us; speedup vs baseline: 1.0199x; 1.0199x over previous
//
#include <hip/hip_runtime.h>

// Fused multi-graph GCN inference (N=320k, E=5.12M, features 1->16->16->8->1).
// Layer-1 collapses to a scalar per node; layer-2 uses the relu-threshold bucket
// trick. Edges counting-sorted by dst-range (1024/range), marked-dst edges first.
// R13: k_bucket reverted to R11's clsL form (binary-search sweep was slower);
// k_degR2/k_t1R2/k_cmap_hist get explicit next-iteration prefetch (the loops were
// load->dependent-LDS-atomic chains eating full memory latency per iteration).

#define MAXB 17
#define RS_BITS 10
#define RS (1 << RS_BITS)
#define SRC_BITS 19
#define SRC_MASK ((1u << SRC_BITS) - 1u)
#define SENT 0xFFFFFFFFu
#define CMAX 160
#define RMAX 320                 // max ranges for new path (N <= 327,680)
#define NPGW_MAX 512             // npg <= 16384
#define HB 512                   // hist blocks
#define BK_BT 512
#define BK_EPT 16
#define BK_TILE (BK_BT * BK_EPT) // 8192
#define PAD4(x) (((x) + 3) & ~3)

__device__ __forceinline__ int div_npg(int d, unsigned long long magic) {
    return (int)(((unsigned long long)(unsigned)d * magic) >> 45);  // exact for d < 2^19
}

__global__ void k_fill_f(float* __restrict__ w, float v, int n) {
    int i = blockIdx.x * blockDim.x + threadIdx.x;
    if (i < n) w[i] = v;
}
__global__ void k_fill_i(int* __restrict__ w, int v, int n) {
    int i = blockIdx.x * blockDim.x + threadIdx.x;
    if (i < n) w[i] = v;
}

// One block: relu-threshold prep + gene table/bitmap + zero hist arrays.
__global__ void k_gprep(const float* __restrict__ W1, const float* __restrict__ b1,
                        const int* __restrict__ gene_idx,
                        float* __restrict__ bnd, int* __restrict__ prepI,
                        int* __restrict__ gmap, unsigned* __restrict__ gbit,
                        int* __restrict__ histT, int* __restrict__ histM,
                        int G, int npg, int npgw, int R) {
    int t = threadIdx.x;
    for (int i = t; i < npg; i += 256) gmap[i] = -1;
    for (int i = t; i < npgw; i += 256) gbit[i] = 0;
    for (int i = t; i < R; i += 256) { histT[i] = 0; histM[i] = 0; }
    __syncthreads();
    for (int g = t; g < G; g += 256) {
        int gi = gene_idx[g];
        if ((unsigned)gi < (unsigned)npg) {
            gmap[gi] = g;
            atomicOr(&gbit[gi >> 5], 1u << (gi & 31));
        }
    }
    if (t != 0) return;
    float tt[16]; int type[16]; int pos[16];
    float thr[16]; int nt = 0;
    for (int j = 0; j < 16; j++) {
        float W = W1[j], B = b1[j];
        if (W > 0.f)      { type[j] = 0; tt[j] = -B / W; }
        else if (W < 0.f) { type[j] = 1; tt[j] = -B / W; }
        else              { type[j] = (B > 0.f) ? 2 : 3; tt[j] = 0.f; }
    }
    for (int j = 0; j < 16; j++) {
        if (type[j] > 1) continue;
        float v = tt[j];
        int k = 0; while (k < nt && thr[k] < v) k++;
        if (!(k < nt && thr[k] == v)) {
            for (int m = nt; m > k; m--) thr[m] = thr[m - 1];
            thr[k] = v; nt++;
        }
    }
    int K = nt + 1;
    for (int j = 0; j < 16; j++) {
        if (type[j] <= 1) { int k = 0; while (thr[k] != tt[j]) k++; pos[j] = k; }
        else pos[j] = 0;
    }
    for (int k = 0; k < 16; k++) bnd[k] = (k < nt) ? thr[k] : 3.4e38f;
    prepI[0] = K;
    for (int k = 0; k < K; k++) {
        unsigned m = 0;
        for (int j = 0; j < 16; j++) {
            bool act;
            if (type[j] == 0)      act = (k >= pos[j] + 1);
            else if (type[j] == 1) act = (k <= pos[j]);
            else                   act = (type[j] == 2);
            if (act) m |= (1u << j);
        }
        prepI[1 + k] = (int)m;
    }
}

// Fused: blocks [0,R) build cmap/cslot/mc; blocks [R,R+HB) histogram dst ranges.
// Hist loop prefetches the next int4 while classifying the current one.
__global__ void k_cmap_hist(const int* __restrict__ gmap, const unsigned* __restrict__ gbit,
                            const int* __restrict__ dst,
                            int* __restrict__ cm, int* __restrict__ cslot, int* __restrict__ mc,
                            int* __restrict__ histT, int* __restrict__ histM,
                            int N, int R, int npg, int reps, int G, int E, int npgw,
                            unsigned long long magic) {
    __shared__ unsigned bitL[NPGW_MAX];
    for (int i = threadIdx.x; i < npgw; i += 256) bitL[i] = gbit[i];
    if (blockIdx.x < (unsigned)R) {
        __shared__ int cnt;
        if (threadIdx.x == 0) cnt = 0;
        __syncthreads();
        int r = blockIdx.x;
        int b0 = r << RS_BITS;
        for (int i = threadIdx.x; i < RS; i += 256) {
            int v = b0 + i;
            if (v >= N) continue;
            int rep = div_npg(v, magic);
            int gi = v - rep * npg;
            int out = -1;
            if (rep < reps && ((bitL[gi >> 5] >> (gi & 31)) & 1u)) {
                int g = gmap[gi];
                if (g >= 0) {
                    int sl = rep * G + g;
                    int c = atomicAdd(&cnt, 1);
                    if (c < CMAX) { cslot[r * CMAX + c] = sl; out = c; }
                    else out = -(sl + 2);
                }
            }
            cm[v] = out;
        }
        __syncthreads();
        if (threadIdx.x == 0) mc[r] = min(cnt, CMAX);
    } else {
        __shared__ int hT[RMAX], hM[RMAX];
        for (int i = threadIdx.x; i < R; i += 256) { hT[i] = 0; hM[i] = 0; }
        __syncthreads();
        int hb = blockIdx.x - R;
        int stride = HB * 256;
        int E4 = E >> 2;
        const int4* d4p = (const int4*)dst;
        int e = hb * 256 + threadIdx.x;
        if (e < E4) {
            int4 cur = d4p[e];
            while (e < E4) {
                int en = e + stride;
                int4 nxt;
                if (en < E4) nxt = d4p[en];           // prefetch next iteration
                int dd[4] = {cur.x, cur.y, cur.z, cur.w};
#pragma unroll
                for (int k = 0; k < 4; k++) {
                    int d = dd[k];
                    if ((unsigned)d >= (unsigned)N) continue;
                    atomicAdd(&hT[d >> RS_BITS], 1);
                    int rep = div_npg(d, magic);
                    int gi = d - rep * npg;
                    if (rep < reps && ((bitL[gi >> 5] >> (gi & 31)) & 1u))
                        atomicAdd(&hM[d >> RS_BITS], 1);
                }
                e = en; cur = nxt;
            }
        }
        for (int e2 = (E4 << 2) + hb * 256 + threadIdx.x; e2 < E; e2 += stride) {
            int d = dst[e2];
            if ((unsigned)d >= (unsigned)N) continue;
            atomicAdd(&hT[d >> RS_BITS], 1);
            int rep = div_npg(d, magic);
            int gi = d - rep * npg;
            if (rep < reps && ((bitL[gi >> 5] >> (gi & 31)) & 1u))
                atomicAdd(&hM[d >> RS_BITS], 1);
        }
        __syncthreads();
        for (int i = threadIdx.x; i < R; i += 256) {
            if (hT[i]) atomicAdd(&histT[i], hT[i]);
            if (hM[i]) atomicAdd(&histM[i], hM[i]);
        }
    }
}

// Scan padded segment sizes; init packed cursors; write pad-gap sentinels (<=6/range).
__global__ void k_scan(const int* __restrict__ histT, const int* __restrict__ histM,
                       int* __restrict__ baseA, unsigned long long* __restrict__ cur64,
                       unsigned* __restrict__ bucket, int R, int cap) {
    __shared__ int a[512];
    int t = threadIdx.x;
    int m = (t < R) ? histM[t] : 0;
    int tot = (t < R) ? histT[t] : 0;
    int u = tot - m; if (u < 0) u = 0;
    int seg = PAD4(m) + PAD4(u);
    a[t] = seg;
    __syncthreads();
    for (int off = 1; off < 512; off <<= 1) {
        int add = (t >= off) ? a[t - off] : 0;
        __syncthreads();
        a[t] += add;
        __syncthreads();
    }
    if (t < R) {
        int base = a[t] - seg;
        baseA[t] = base;
        int mstart = base, ustart = base + PAD4(m);
        cur64[t] = (unsigned long long)(unsigned)mstart |
                   ((unsigned long long)(unsigned)ustart << 32);
        for (int i = m; i < PAD4(m); i++) { int ix = mstart + i; if (ix < cap) bucket[ix] = SENT; }
        for (int i = u; i < PAD4(u); i++) { int ix = ustart + i; if (ix < cap) bucket[ix] = SENT; }
    }
}

// Dual-class bucket scatter with per-tile LDS counting sort + coalesced sweep.
// R11 form: clsL array records each sorted slot's class (no binary search).
__global__ void __launch_bounds__(BK_BT)
k_bucket(const int* __restrict__ src, const int* __restrict__ dst,
         const unsigned* __restrict__ gbit, unsigned long long* __restrict__ cur64,
         unsigned* __restrict__ bucket, int E, int N, int R, int cap,
         int npg, int reps, int npgw, unsigned long long magic) {
    __shared__ unsigned bitL[NPGW_MAX];
    __shared__ int cntA[RMAX];                   // packed m|u<<16 counts
    __shared__ int cnt2[RMAX];                   // packed placement counters
    __shared__ int eb[2 * RMAX];                 // class exclusive bases (sorted order)
    __shared__ int dl[2 * RMAX];                 // global - local delta per class
    __shared__ unsigned sortL[BK_TILE];          // 32 KB
    __shared__ unsigned short clsL[BK_TILE];     // 16 KB
    __shared__ int totalS;

    for (int i = threadIdx.x; i < npgw; i += BK_BT) bitL[i] = gbit[i];
    for (int i = threadIdx.x; i < R; i += BK_BT) { cntA[i] = 0; cnt2[i] = 0; }
    __syncthreads();

    int tile0 = blockIdx.x * BK_TILE;
    int rr[BK_EPT]; unsigned val[BK_EPT]; unsigned mbits = 0;
    // phase 1: read + classify + per-range packed count
#pragma unroll
    for (int c = 0; c < 4; c++) {
        int e0 = tile0 + c * (BK_BT * 4) + threadIdx.x * 4;
        int dd[4], ss[4];
        if (e0 + 3 < E) {
            int4 d4 = *(const int4*)(dst + e0);
            int4 s4 = *(const int4*)(src + e0);
            dd[0] = d4.x; dd[1] = d4.y; dd[2] = d4.z; dd[3] = d4.w;
            ss[0] = s4.x; ss[1] = s4.y; ss[2] = s4.z; ss[3] = s4.w;
        } else {
#pragma unroll
            for (int k = 0; k < 4; k++) {
                int e = e0 + k;
                dd[k] = (e < E) ? dst[e] : -1;
                ss[k] = (e < E) ? src[e] : -1;
            }
        }
#pragma unroll
        for (int k = 0; k < 4; k++) {
            int idx = c * 4 + k;
            int d = dd[k];
            rr[idx] = -1;
            if ((unsigned)d < (unsigned)N) {
                int rep = div_npg(d, magic);
                int gi = d - rep * npg;
                unsigned m = (rep < reps && ((bitL[gi >> 5] >> (gi & 31)) & 1u)) ? 1u : 0u;
                int s = ss[k];
                rr[idx] = d >> RS_BITS;
                val[idx] = ((unsigned)s < (unsigned)N)
                               ? (((unsigned)(d & (RS - 1)) << SRC_BITS) | (unsigned)s)
                               : SENT;
                mbits |= m << idx;
                atomicAdd(&cntA[d >> RS_BITS], m ? 1 : (1 << 16));
            }
        }
    }
    __syncthreads();
    // phase 2: scan 2R class counts (marked classes [0,R), unmarked [R,2R))
    int n2 = 2 * R;
    for (int i = threadIdx.x; i < n2; i += BK_BT)
        eb[i] = (i < R) ? (cntA[i] & 0xFFFF) : (cntA[i - R] >> 16);
    __syncthreads();
    for (int off = 1; off < n2; off <<= 1) {
        int i0 = threadIdx.x, i1 = threadIdx.x + BK_BT;
        int t0 = 0, t1 = 0;
        if (i0 < n2 && i0 >= off) t0 = eb[i0 - off];
        if (i1 < n2 && i1 >= off) t1 = eb[i1 - off];
        __syncthreads();
        if (i0 < n2) eb[i0] += t0;
        if (i1 < n2) eb[i1] += t1;
        __syncthreads();
    }
    if (threadIdx.x == 0) totalS = eb[n2 - 1];
    {   // inclusive -> exclusive
        int i0 = threadIdx.x, i1 = threadIdx.x + BK_BT;
        int c0 = 0, c1 = 0;
        if (i0 < n2) c0 = (i0 < R) ? (cntA[i0] & 0xFFFF) : (cntA[i0 - R] >> 16);
        if (i1 < n2) c1 = (i1 < R) ? (cntA[i1] & 0xFFFF) : (cntA[i1 - R] >> 16);
        __syncthreads();
        if (i0 < n2) eb[i0] -= c0;
        if (i1 < n2) eb[i1] -= c1;
    }
    __syncthreads();
    // phase 3: one packed 64-bit global reservation per range; deltas per class
    for (int r = threadIdx.x; r < R; r += BK_BT) {
        int c = cntA[r];
        if (c) {
            unsigned long long add = (unsigned long long)(c & 0xFFFF) |
                                     ((unsigned long long)(unsigned)(c >> 16) << 32);
            unsigned long long old = atomicAdd(&cur64[r], add);
            dl[r]     = (int)(old & 0xFFFFFFFFull) - eb[r];
            dl[R + r] = (int)(old >> 32)           - eb[R + r];
        }
    }
    __syncthreads();
    // phase 4: place into LDS in class-major sorted order
#pragma unroll
    for (int i = 0; i < BK_EPT; i++) {
        int r = rr[i];
        if (r < 0) continue;
        unsigned m = (mbits >> i) & 1u;
        int o = atomicAdd(&cnt2[r], m ? 1 : (1 << 16));
        int cidx = m ? r : (R + r);
        int loc = m ? (o & 0xFFFF) : (o >> 16);
        int pos = eb[cidx] + loc;
        sortL[pos] = val[i];
        clsL[pos] = (unsigned short)cidx;
    }
    __syncthreads();
    // phase 5: coalesced linear sweep to global
    int total = totalS;
    for (int i = threadIdx.x; i < total; i += BK_BT) {
        int cidx = clsL[i];
        int addr = dl[cidx] + i;
        if ((unsigned)addr < (unsigned)cap) bucket[addr] = sortL[i];
    }
}

// ---------- sub-blocked per-range passes (prefetched) ----------

// All segment bounds are 4-aligned (segments and sub-block splits are &~3,
// cap/base 4-aligned), so inner per-element bounds checks are dropped;
// SENT pads cover the tails.

__global__ void __launch_bounds__(1024)
k_degR2(const unsigned* __restrict__ bucket, const int* __restrict__ baseA,
        const int* __restrict__ histT, const int* __restrict__ histM,
        int* __restrict__ pDeg, int cap, int S) {
    __shared__ int degL[RS];
    int r = blockIdx.x / S, q = blockIdx.x % S;
    int m = histM[r];
    int u = histT[r] - m; if (u < 0) u = 0;
    int nb = baseA[r];
    int len = min(PAD4(m) + PAD4(u), cap - nb);
    if (len < 0) len = 0;
    int lo = (int)(((long long)len * q / S) & ~3LL);
    int hi = (q == S - 1) ? len : (int)(((long long)len * (q + 1) / S) & ~3LL);
    for (int i = threadIdx.x; i < RS; i += blockDim.x) degL[i] = 0;
    __syncthreads();
    int stride = blockDim.x * 4;
    int i = lo + threadIdx.x * 4;
    if (i < hi) {
        uint4 cur = *(const uint4*)(bucket + nb + i);
        while (i < hi) {
            int in = i + stride;
            uint4 nxt;
            if (in < hi) nxt = *(const uint4*)(bucket + nb + in);  // prefetch
            if (cur.x != SENT) atomicAdd(&degL[cur.x >> SRC_BITS], 1);
            if (cur.y != SENT) atomicAdd(&degL[cur.y >> SRC_BITS], 1);
            if (cur.z != SENT) atomicAdd(&degL[cur.z >> SRC_BITS], 1);
            if (cur.w != SENT) atomicAdd(&degL[cur.w >> SRC_BITS], 1);
            i = in; cur = nxt;
        }
    }
    __syncthreads();
    int* out = pDeg + (size_t)(r * S + q) * RS;
    for (int j = threadIdx.x; j < RS; j += blockDim.x) out[j] = degL[j];
}

__global__ void k_dinvp2(const int* __restrict__ pDeg, const float* __restrict__ x,
                         float* __restrict__ sd, float* __restrict__ p, int N, int S) {
    int v = blockIdx.x * blockDim.x + threadIdx.x;
    if (v >= N) return;
    int r = v >> RS_BITS, l = v & (RS - 1);
    int deg = 0;
    for (int q = 0; q < S; q++) deg += pDeg[(size_t)(r * S + q) * RS + l];
    float di = rsqrtf((float)deg + 1.0f);
    sd[2 * v + 1] = di;
    p[v] = x[v] * di;
}

__global__ void __launch_bounds__(1024)
k_t1R2(const unsigned* __restrict__ bucket, const int* __restrict__ baseA,
       const int* __restrict__ histT, const int* __restrict__ histM,
       const float* __restrict__ p, float* __restrict__ pT1, int cap, int S) {
    __shared__ float accL[RS];
    int r = blockIdx.x / S, q = blockIdx.x % S;
    int m = histM[r];
    int u = histT[r] - m; if (u < 0) u = 0;
    int nb = baseA[r];
    int len = min(PAD4(m) + PAD4(u), cap - nb);
    if (len < 0) len = 0;
    int lo = (int)(((long long)len * q / S) & ~3LL);
    int hi = (q == S - 1) ? len : (int)(((long long)len * (q + 1) / S) & ~3LL);
    for (int i = threadIdx.x; i < RS; i += blockDim.x) accL[i] = 0.f;
    __syncthreads();
    int stride = blockDim.x * 4;
    int i = lo + threadIdx.x * 4;
    if (i < hi) {
        uint4 cur = *(const uint4*)(bucket + nb + i);
        while (i < hi) {
            int in = i + stride;
            uint4 nxt;
            if (in < hi) nxt = *(const uint4*)(bucket + nb + in);  // prefetch
            // issue the 4 independent gathers, then the LDS atomics
            float v0 = (cur.x != SENT) ? p[cur.x & SRC_MASK] : 0.f;
            float v1 = (cur.y != SENT) ? p[cur.y & SRC_MASK] : 0.f;
            float v2 = (cur.z != SENT) ? p[cur.z & SRC_MASK] : 0.f;
            float v3 = (cur.w != SENT) ? p[cur.w & SRC_MASK] : 0.f;
            if (cur.x != SENT) atomicAdd(&accL[cur.x >> SRC_BITS], v0);
            if (cur.y != SENT) atomicAdd(&accL[cur.y >> SRC_BITS], v1);
            if (cur.z != SENT) atomicAdd(&accL[cur.z >> SRC_BITS], v2);
            if (cur.w != SENT) atomicAdd(&accL[cur.w >> SRC_BITS], v3);
            i = in; cur = nxt;
        }
    }
    __syncthreads();
    float* out = pT1 + (size_t)(r * S + q) * RS;
    for (int j = threadIdx.x; j < RS; j += blockDim.x) out[j] = accL[j];
}

// s[v] = dinv*(t1+p) -> sd[2v]; also zero-fills aggb8.
__global__ void k_s3(const float* __restrict__ pT1, const float* __restrict__ p,
                     float* __restrict__ sd, float* __restrict__ aggb8, int n8,
                     int N, int S) {
    int v = blockIdx.x * blockDim.x + threadIdx.x;
    if (v < n8) aggb8[v] = 0.f;
    if (v >= N) return;
    int r = v >> RS_BITS, l = v & (RS - 1);
    float t1 = 0.f;
    for (int q = 0; q < S; q++) t1 += pT1[(size_t)(r * S + q) * RS + l];
    sd[2 * v] = sd[2 * v + 1] * (t1 + p[v]);
}

// Layer-2 bucket sums over marked prefix (K<=4; compact rows -> plain stores).
// K>4: grid-stride zero of wide; subsequent k_agg_atomic accumulates into it.
__global__ void k_aggS(const unsigned* __restrict__ bucket, const int* __restrict__ baseA,
                       const int* __restrict__ histM,
                       const float* __restrict__ sd, const int* __restrict__ cm,
                       const int* __restrict__ cslot, const int* __restrict__ mc,
                       const float* __restrict__ bnd, const int* __restrict__ prepI,
                       float* __restrict__ aggb8, float* __restrict__ wide, int wn,
                       int N, int cap) {
    __shared__ float acc[CMAX * 8];
    __shared__ int cmapL[RS];
    __shared__ float sB[3];
    __shared__ int sK;
    if (threadIdx.x == 0) sK = prepI[0];
    if (threadIdx.x < 3) sB[threadIdx.x] = bnd[threadIdx.x];
    __syncthreads();
    int K = sK;
    if (K > 4) {
        for (int i = blockIdx.x * blockDim.x + threadIdx.x; i < wn;
             i += gridDim.x * blockDim.x)
            wide[i] = 0.f;
        return;
    }
    int r = blockIdx.x;
    int b0 = r << RS_BITS;
    for (int i = threadIdx.x; i < RS; i += 256) {
        int v = b0 + i;
        cmapL[i] = (v < N) ? cm[v] : -1;
    }
    for (int i = threadIdx.x; i < CMAX * 8; i += 256) acc[i] = 0.f;
    __syncthreads();
    int nb = baseA[r];
    int mlen = min(histM[r], cap - nb);
    if (mlen < 0) mlen = 0;
    const float2* sd2 = (const float2*)sd;
    for (int i = threadIdx.x * 4; i < mlen; i += 256 * 4) {
        uint4 e4 = *(const uint4*)(bucket + nb + i);
        unsigned ee[4] = {e4.x, e4.y, e4.z, e4.w};
#pragma unroll
        for (int k4 = 0; k4 < 4; k4++) {
            if (i + k4 >= mlen) break;
            unsigned e = ee[k4];
            if (e == SENT) continue;
            int c = cmapL[e >> SRC_BITS];
            if (c == -1) continue;
            float2 v = sd2[e & SRC_MASK];
            int b = 0;
            for (int k = 0; k < K - 1; k++) b += (v.x > sB[k]) ? 1 : 0;
            if (c >= 0) {
                atomicAdd(&acc[c * 8 + 2 * b], v.x * v.y);
                atomicAdd(&acc[c * 8 + 2 * b + 1], v.y);
            } else {
                int sl = -(c + 2);
                atomicAdd(&aggb8[(size_t)sl * 8 + 2 * b], v.x * v.y);
                atomicAdd(&aggb8[(size_t)sl * 8 + 2 * b + 1], v.y);
            }
        }
    }
    __syncthreads();
    int mcR = mc[r];
    for (int idx = threadIdx.x; idx < mcR * 8; idx += 256) {
        int c = idx >> 3, j = idx & 7;
        int sl = cslot[r * CMAX + c];
        if (sl >= 0) aggb8[(size_t)sl * 8 + j] = acc[idx];
    }
}

// ---------- generic / fallback kernels ----------

__global__ void k_mark(const int* __restrict__ gene_idx, int* __restrict__ slot,
                       int G, int M, int npg, int N) {
    int i = blockIdx.x * blockDim.x + threadIdx.x;
    if (i >= M) return;
    int node = gene_idx[i % G] + (i / G) * npg;
    if ((unsigned)node < (unsigned)N) slot[node] = i;
}

__global__ void k_deg(const int* __restrict__ dst, float* __restrict__ deg, int E, int N) {
    int e = blockIdx.x * blockDim.x + threadIdx.x;
    if (e >= E) return;
    int d = dst[e];
    if ((unsigned)d < (unsigned)N) atomicAdd(&deg[d], 1.0f);
}

__global__ void k_dinv_p(const float* __restrict__ x, float* __restrict__ degv,
                         float* __restrict__ p, int N) {
    int v = blockIdx.x * blockDim.x + threadIdx.x;
    if (v < N) {
        float di = rsqrtf(degv[v] + 1.0f);
        degv[v] = di;
        p[v] = x[v] * di;
    }
}

__global__ void k_scatter1(const int* __restrict__ src, const int* __restrict__ dst,
                           const float* __restrict__ p, float* __restrict__ t1, int E, int N) {
    int e = blockIdx.x * blockDim.x + threadIdx.x;
    if (e >= E) return;
    int s = src[e];
    int d = dst[e];
    if ((unsigned)s < (unsigned)N && (unsigned)d < (unsigned)N)
        atomicAdd(&t1[d], p[s]);
}

__global__ void k_s(const float* __restrict__ p, const float* __restrict__ dinv,
                    float* __restrict__ t1, int N) {
    int v = blockIdx.x * blockDim.x + threadIdx.x;
    if (v < N) t1[v] = dinv[v] * (t1[v] + p[v]);
}

__global__ void k_agg_atomic(const int* __restrict__ src, const int* __restrict__ dst,
                             const float* __restrict__ sA, const float* __restrict__ dA,
                             int str, const int* __restrict__ cm, const int* __restrict__ cslot,
                             const float* __restrict__ bnd, const int* __restrict__ prepI,
                             float* __restrict__ wide, int E, int N, int force, int mode) {
    __shared__ float sB[16];
    __shared__ int sK;
    if (threadIdx.x == 0) sK = prepI[0];
    if (threadIdx.x < 16) sB[threadIdx.x] = bnd[threadIdx.x];
    __syncthreads();
    int K = sK;
    if (!force && K <= 4) return;
    int T = K - 1;
    for (int e = blockIdx.x * blockDim.x + threadIdx.x; e < E; e += gridDim.x * blockDim.x) {
        int d = dst[e];
        if ((unsigned)d >= (unsigned)N) continue;
        int c = cm[d];
        int sl;
        if (mode == 0) sl = c;
        else sl = (c >= 0) ? cslot[(d >> RS_BITS) * CMAX + c] : (c <= -2 ? -(c + 2) : -1);
        if (sl < 0) continue;
        int sv = src[e];
        if ((unsigned)sv >= (unsigned)N) continue;
        float sval = sA[(size_t)sv * str];
        float di = dA[(size_t)sv * str];
        int b = 0;
        for (int i = 0; i < T; i++) b += (sval > sB[i]) ? 1 : 0;
        float* row = wide + (size_t)sl * (2 * MAXB) + 2 * b;
        atomicAdd(row, sval * di);
        atomicAdd(row + 1, di);
    }
}

__global__ void k_final(const float* __restrict__ aggb8, const float* __restrict__ wide,
                        const float* __restrict__ sA, const float* __restrict__ dA, int str,
                        const int* __restrict__ gene_idx, const int* __restrict__ cm,
                        const int* __restrict__ cslot, const int* __restrict__ prepI,
                        const float* __restrict__ W1, const float* __restrict__ b1,
                        const float* __restrict__ W2, const float* __restrict__ b2,
                        const float* __restrict__ f1W, const float* __restrict__ f1b,
                        const float* __restrict__ f2W, const float* __restrict__ f2b,
                        float* __restrict__ out, int G, int M, int npg, int N, int mode) {
    __shared__ float sW1[16], sb1[16], sW2[256], sb2[16], sf1[128], sf1b[8], sf2[8], sf2b[1];
    __shared__ int sMask[MAXB], sK;
    for (int i = threadIdx.x; i < 256; i += blockDim.x) sW2[i] = W2[i];
    for (int i = threadIdx.x; i < 128; i += blockDim.x) sf1[i] = f1W[i];
    if (threadIdx.x < 16) { sW1[threadIdx.x] = W1[threadIdx.x]; sb1[threadIdx.x] = b1[threadIdx.x]; sb2[threadIdx.x] = b2[threadIdx.x]; }
    if (threadIdx.x < 8)  { sf1b[threadIdx.x] = f1b[threadIdx.x]; sf2[threadIdx.x] = f2W[threadIdx.x]; }
    if (threadIdx.x == 0) { sf2b[0] = f2b[0]; sK = prepI[0]; }
    if (threadIdx.x < MAXB) sMask[threadIdx.x] = prepI[1 + threadIdx.x];
    __syncthreads();

    int i = blockIdx.x * blockDim.x + threadIdx.x;
    if (i >= M) return;
    int node = gene_idx[i % G] + (i / G) * npg;
    if ((unsigned)node >= (unsigned)N) { out[i] = 0.0f; return; }
    int K = sK;
    int c = cm[node];
    int sl;
    if (mode == 0) sl = c;
    else sl = (c >= 0) ? cslot[(node >> RS_BITS) * CMAX + c] : (c <= -2 ? -(c + 2) : -1);

    float di = dA[(size_t)node * str];
    float sval = sA[(size_t)node * str];

    float bu[MAXB], bw[MAXB];
    if (sl >= 0) {
        const float* row = (mode == 1 && K <= 4) ? (aggb8 + (size_t)sl * 8)
                                                 : (wide + (size_t)sl * (2 * MAXB));
        for (int k = 0; k < K; k++) { bu[k] = row[2 * k]; bw[k] = row[2 * k + 1]; }
    } else {
        for (int k = 0; k < K; k++) { bu[k] = 0.f; bw[k] = 0.f; }
    }

    float a[16];
#pragma unroll
    for (int j = 0; j < 16; j++) {
        float Su = 0.f, Sw = 0.f;
        for (int k = 0; k < K; k++) {
            if ((sMask[k] >> j) & 1) { Su += bu[k]; Sw += bw[k]; }
        }
        float aggj = sW1[j] * Su + sb1[j] * Sw;
        float qself = fmaxf(fmaf(sW1[j], sval, sb1[j]), 0.0f) * di;
        a[j] = di * (aggj + qself);
    }
    float h2[16];
#pragma unroll
    for (int j = 0; j < 16; j++) {
        float acc = sb2[j];
#pragma unroll
        for (int k = 0; k < 16; k++) acc = fmaf(a[k], sW2[k * 16 + j], acc);
        h2[j] = fmaxf(acc, 0.0f);
    }
    float f1[8];
#pragma unroll
    for (int j = 0; j < 8; j++) {
        float acc = sf1b[j];
#pragma unroll
        for (int k = 0; k < 16; k++) acc = fmaf(h2[k], sf1[k * 8 + j], acc);
        f1[j] = fmaxf(acc, 0.0f);
    }
    float o = sf2b[0];
#pragma unroll
    for (int k = 0; k < 8; k++) o = fmaf(f1[k], sf2[k], o);
    out[i] = o;
}

extern "C" void kernel_launch(void* const* d_in, const int* in_sizes, int n_in,
                              void* d_out, int out_size, void* d_ws, size_t ws_size,
                              hipStream_t stream) {
    const float* x        = (const float*)d_in[0];
    const int*   ei       = (const int*)d_in[1];
    const int*   gene_idx = (const int*)d_in[3];
    const float* W1  = (const float*)d_in[5];
    const float* b1  = (const float*)d_in[6];
    const float* W2  = (const float*)d_in[7];
    const float* b2  = (const float*)d_in[8];
    const float* f1W = (const float*)d_in[9];
    const float* f1b = (const float*)d_in[10];
    const float* f2W = (const float*)d_in[11];
    const float* f2b = (const float*)d_in[12];
    float* out = (float*)d_out;

    int N = in_sizes[0];       // 320000
    int E = in_sizes[1] / 2;   // 5120000
    int M = in_sizes[2];       // 32000
    int G = in_sizes[3];       // 1000
    int npg = (int)(((long long)N * (long long)G) / (long long)M);
    int reps = (G > 0) ? M / G : 0;
    int npgw = (npg + 31) / 32;
    unsigned long long magic = (npg >= 1) ? (((1ULL << 45) + npg - 1) / (unsigned)npg) : 1;

    const int* src = ei;
    const int* dst = ei + E;

    int R = (N + RS - 1) >> RS_BITS;
    int cap = E + 8 * R + 8;
    const int tb = 256;
    int wn = 2 * MAXB * M;

    float* ws = (float*)d_ws;
    size_t off = 0;
    float*    sd     = ws + off;              off += (size_t)2 * N;
    int*      cm     = (int*)(ws + off);      off += (size_t)N;
    float*    p      = ws + off;              off += (size_t)N;
    float*    aggb8  = ws + off;              off += (size_t)8 * M;
    unsigned* bucket = (unsigned*)(ws + off); off += (size_t)cap;
    int*      gmap   = (int*)(ws + off);      off += (size_t)npg;
    unsigned* gbit   = (unsigned*)(ws + off); off += (size_t)npgw;
    int*      cslot  = (int*)(ws + off);      off += (size_t)R * CMAX;
    int*      mc     = (int*)(ws + off);      off += (size_t)R;
    int*      histT  = (int*)(ws + off);      off += (size_t)R;
    int*      histM  = (int*)(ws + off);      off += (size_t)R;
    int*      baseA  = (int*)(ws + off);      off += (size_t)R;
    off = (off + 1) & ~(size_t)1;             // 8B align
    unsigned long long* cur64 = (unsigned long long*)(ws + off); off += (size_t)2 * R;
    float*    bnd    = ws + off;              off += 16;
    int*      prepI  = (int*)(ws + off);      off += 20;
    size_t base_need = off;

    int S = 4;
    while (S > 1 && (base_need + (size_t)R * S * RS) * 4 > ws_size) S >>= 1;
    float* partial = ws + base_need;
    int*   partialI = (int*)partial;
    float* wide = partial;                    // overlays partial (dead after k_s3)
    size_t need = (base_need + (size_t)R * S * RS) * 4;

    bool use_new = (need <= ws_size) && (N < (1 << SRC_BITS)) && (R <= RMAX) &&
                   (npg >= 1) && (npg <= NPGW_MAX * 32) && (reps >= 1) &&
                   ((size_t)R * S * RS >= (size_t)wn);

    if (use_new) {
        int BTr = (S == 1) ? 1024 : 256;
        k_gprep<<<1, 256, 0, stream>>>(W1, b1, gene_idx, bnd, prepI, gmap, gbit,
                                       histT, histM, G, npg, npgw, R);
        k_cmap_hist<<<R + HB, 256, 0, stream>>>(gmap, gbit, dst, cm, cslot, mc,
                                                histT, histM, N, R, npg, reps, G, E,
                                                npgw, magic);
        k_scan<<<1, 512, 0, stream>>>(histT, histM, baseA, cur64, bucket, R, cap);
        int ntiles = (E + BK_TILE - 1) / BK_TILE;
        k_bucket<<<ntiles, BK_BT, 0, stream>>>(src, dst, gbit, cur64, bucket,
                                               E, N, R, cap, npg, reps, npgw, magic);
        k_degR2<<<R * S, BTr, 0, stream>>>(bucket, baseA, histT, histM, partialI, cap, S);
        k_dinvp2<<<(N + tb - 1) / tb, tb, 0, stream>>>(partialI, x, sd, p, N, S);
        k_t1R2<<<R * S, BTr, 0, stream>>>(bucket, baseA, histT, histM, p, partial, cap, S);
        int n8 = 8 * M;
        int s3grid = ((N > n8 ? N : n8) + tb - 1) / tb;
        k_s3<<<s3grid, tb, 0, stream>>>(partial, p, sd, aggb8, n8, N, S);
        k_aggS<<<R, tb, 0, stream>>>(bucket, baseA, histM, sd, cm, cslot, mc,
                                     bnd, prepI, aggb8, wide, wn, N, cap);
        k_agg_atomic<<<512, tb, 0, stream>>>(src, dst, sd, sd + 1, 2, cm, cslot, bnd,
                                             prepI, wide, E, N, /*force=*/0, /*mode=*/1);
        k_final<<<(M + tb - 1) / tb, tb, 0, stream>>>(aggb8, wide, sd, sd + 1, 2, gene_idx,
                                                      cm, cslot, prepI, W1, b1, W2, b2,
                                                      f1W, f1b, f2W, f2b, out, G, M, npg, N,
                                                      /*mode=*/1);
    } else {
        // Fallback: global-atomic path, wide layout.
        float* deg   = ws;
        float* t1o   = ws + (size_t)N;
        float* pO    = ws + 2 * (size_t)N;
        int*   slotO = (int*)(ws + 3 * (size_t)N);
        float* wideO = ws + 4 * (size_t)N;
        float* bndO  = wideO + (size_t)wn;
        int*   prepO = (int*)(bndO + 16);
        int*   scr   = prepO + 20;

        k_fill_f<<<(2 * N + tb - 1) / tb, tb, 0, stream>>>(deg, 0.0f, 2 * N);
        k_fill_i<<<(N + tb - 1) / tb, tb, 0, stream>>>(slotO, -1, N);
        k_fill_f<<<(wn + tb - 1) / tb, tb, 0, stream>>>(wideO, 0.0f, wn);
        k_gprep<<<1, 256, 0, stream>>>(W1, b1, gene_idx, bndO, prepO,
                                       scr, (unsigned*)(scr + 1), scr + 2, scr + 3,
                                       0, 1, 1, 0);
        k_mark<<<(M + tb - 1) / tb, tb, 0, stream>>>(gene_idx, slotO, G, M, npg, N);
        k_deg<<<(E + tb - 1) / tb, tb, 0, stream>>>(dst, deg, E, N);
        k_dinv_p<<<(N + tb - 1) / tb, tb, 0, stream>>>(x, deg, pO, N);
        k_scatter1<<<(E + tb - 1) / tb, tb, 0, stream>>>(src, dst, pO, t1o, E, N);
        k_s<<<(N + tb - 1) / tb, tb, 0, stream>>>(pO, deg, t1o, N);
        k_agg_atomic<<<2048, tb, 0, stream>>>(src, dst, t1o, deg, 1, slotO, (int*)0, bndO,
                                              prepO, wideO, E, N, /*force=*/1, /*mode=*/0);
        k_final<<<(M + tb - 1) / tb, tb, 0, stream>>>((float*)0, wideO, t1o, deg, 1, gene_idx,
                                                      slotO, (int*)0, prepO, W1, b1, W2, b2,
                                                      f1W, f1b, f2W, f2b, out, G, M, npg, N,
                                                      /*mode=*/0);
    }
}